// Round 3
// baseline (2471.723 us; speedup 1.0000x reference)
//
#include <hip/hip_runtime.h>
#include <hip/hip_bf16.h>
#include <stdint.h>
#include <string.h>

typedef unsigned int u32;
typedef unsigned short u16;

#define NB 8
#define NC 512
#define NCQ 64
#define NH 96
#define NW 96
#define NHW 9216
#define CHW_ 4718592ull      // 512*9216
#define BCHW_ 37748736ull    // 8*512*9216

// ws layout (u16 elems), total 94,371,840 bytes:
// att @0 : [2][B][HW][192] = 28,311,552 elems (0:96 H-part, 96:192 W-part), fp16
// X-region @ATT_E: 18,874,368 elems
//   phase 1: qx @+0, qy @+QK1, kx @+2*QK1, ky @+3*QK1  (each 8*9216*64), fp16
//   phase 2 (after softmax): V-half [B][HW][256] for one input, fp16
#define ATT_E 28311552ull
#define QK1   4718592ull

// fp16 <-> f32 (single v_cvt instructions)
__device__ __forceinline__ float h2f(u16 u){ _Float16 h; __builtin_memcpy(&h, &u, 2); return (float)h; }
__device__ __forceinline__ u16 f2h(float f){ _Float16 h = (_Float16)f; u16 u; __builtin_memcpy(&u, &h, 2); return u; }
__device__ __forceinline__ void unpack8v(uint4 p, float4& a, float4& b){
  a.x = h2f(p.x & 0xffffu); a.y = h2f(p.x >> 16);
  a.z = h2f(p.y & 0xffffu); a.w = h2f(p.y >> 16);
  b.x = h2f(p.z & 0xffffu); b.y = h2f(p.z >> 16);
  b.z = h2f(p.w & 0xffffu); b.w = h2f(p.w >> 16);
}

// ---------------- K1: q,k projections for both inputs, fp16 channel-last store
__global__ __launch_bounds__(256) void proj_qk_kernel(
    const float* __restrict__ x, const float* __restrict__ y,
    const float* __restrict__ Wq, const float* __restrict__ bq,
    const float* __restrict__ Wk, const float* __restrict__ bk,
    u16* __restrict__ ws)
{
  const int tid = threadIdx.x;
  const int ntile = blockIdx.x;            // 0..71 (hw tiles of 128)
  const int b = blockIdx.y >> 1;
  const int t = blockIdx.y & 1;

  const float* __restrict__ X = (t ? y : x) + (size_t)b * CHW_;
  u16* qdst = ws + ATT_E + (t ? QK1 : 0);
  u16* kdst = ws + ATT_E + 2*QK1 + (t ? QK1 : 0);

  __shared__ float Wt[32][132];   // Wt[k][m], m 0..127 (q:0..63, k:64..127)
  __shared__ float Xt[32][128];   // Xt[k][n]

  const int nbase = ntile * 128;
  const int ty = tid >> 4, tx = tid & 15;
  const int m0 = ty * 8;

  float acc[8][8];
  #pragma unroll
  for (int i = 0; i < 8; i++)
    #pragma unroll
    for (int j = 0; j < 8; j++) acc[i][j] = 0.f;

  const int wkq = tid & 7;
  const int wm  = tid >> 3;
  const int xnq = tid & 31;
  const int xkr = tid >> 5;

  for (int k0 = 0; k0 < 512; k0 += 32) {
    #pragma unroll
    for (int r = 0; r < 4; r++) {
      int m = wm + r * 32;
      const float* src = (m < 64) ? (Wq + (size_t)m * 512)
                                  : (Wk + (size_t)(m - 64) * 512);
      float4 wv4 = *(const float4*)(src + k0 + wkq * 4);
      Wt[wkq*4+0][m] = wv4.x;
      Wt[wkq*4+1][m] = wv4.y;
      Wt[wkq*4+2][m] = wv4.z;
      Wt[wkq*4+3][m] = wv4.w;
    }
    #pragma unroll
    for (int r = 0; r < 4; r++) {
      int k = xkr + r * 8;
      float4 xv = *(const float4*)(X + (size_t)(k0 + k) * NHW + nbase + xnq * 4);
      *(float4*)&Xt[k][xnq * 4] = xv;
    }
    __syncthreads();
    #pragma unroll 4
    for (int k = 0; k < 32; k++) {
      float4 a0 = *(const float4*)&Wt[k][m0];
      float4 a1 = *(const float4*)&Wt[k][m0 + 4];
      float4 b0 = *(const float4*)&Xt[k][tx * 4];
      float4 b1 = *(const float4*)&Xt[k][64 + tx * 4];
      float av[8] = {a0.x,a0.y,a0.z,a0.w,a1.x,a1.y,a1.z,a1.w};
      float bv8[8] = {b0.x,b0.y,b0.z,b0.w,b1.x,b1.y,b1.z,b1.w};
      #pragma unroll
      for (int i = 0; i < 8; i++)
        #pragma unroll
        for (int j = 0; j < 8; j++)
          acc[i][j] = fmaf(av[i], bv8[j], acc[i][j]);
    }
    __syncthreads();
  }

  const int M0 = m0;
  u16* dst; const float* bias; int ch0;
  if (M0 < 64) { dst = qdst; bias = bq; ch0 = M0; }
  else         { dst = kdst; bias = bk; ch0 = M0 - 64; }
  float bi[8];
  #pragma unroll
  for (int i = 0; i < 8; i++) bi[i] = bias[ch0 + i];
  #pragma unroll
  for (int jj = 0; jj < 8; jj++) {
    int n = (jj < 4) ? (tx * 4 + jj) : (64 + tx * 4 + (jj - 4));
    size_t hw = (size_t)nbase + n;
    u16* p = dst + ((size_t)b * NHW + hw) * 64 + ch0;
    union { u16 s[8]; uint4 v; } tmp;
    #pragma unroll
    for (int i = 0; i < 8; i++) tmp.s[i] = f2h(acc[i][jj] + bi[i]);
    *(uint4*)p = tmp.v;
  }
}

// ---------------- K1b: v projection, one input (t), one channel-half (chalf)
__global__ __launch_bounds__(256) void proj_v_kernel(
    const float* __restrict__ x, const float* __restrict__ y,
    const float* __restrict__ Wv, const float* __restrict__ bv,
    u16* __restrict__ ws, int t, int chalf)
{
  const int tid = threadIdx.x;
  const int ntile = blockIdx.x;            // 0..71
  const int mtile = blockIdx.y;            // 0..1 (128 channels each)
  const int b = blockIdx.z;

  const float* __restrict__ X = (t ? y : x) + (size_t)b * CHW_;
  u16* vdst = ws + ATT_E;

  __shared__ float Wt[32][132];
  __shared__ float Xt[32][128];

  const int nbase = ntile * 128;
  const int ty = tid >> 4, tx = tid & 15;
  const int m0 = ty * 8;

  float acc[8][8];
  #pragma unroll
  for (int i = 0; i < 8; i++)
    #pragma unroll
    for (int j = 0; j < 8; j++) acc[i][j] = 0.f;

  const int wkq = tid & 7;
  const int wm  = tid >> 3;
  const int xnq = tid & 31;
  const int xkr = tid >> 5;
  const int Wrow0 = chalf * 256 + mtile * 128;

  for (int k0 = 0; k0 < 512; k0 += 32) {
    #pragma unroll
    for (int r = 0; r < 4; r++) {
      int m = wm + r * 32;
      const float* src = Wv + (size_t)(Wrow0 + m) * 512;
      float4 wv4 = *(const float4*)(src + k0 + wkq * 4);
      Wt[wkq*4+0][m] = wv4.x;
      Wt[wkq*4+1][m] = wv4.y;
      Wt[wkq*4+2][m] = wv4.z;
      Wt[wkq*4+3][m] = wv4.w;
    }
    #pragma unroll
    for (int r = 0; r < 4; r++) {
      int k = xkr + r * 8;
      float4 xv = *(const float4*)(X + (size_t)(k0 + k) * NHW + nbase + xnq * 4);
      *(float4*)&Xt[k][xnq * 4] = xv;
    }
    __syncthreads();
    #pragma unroll 4
    for (int k = 0; k < 32; k++) {
      float4 a0 = *(const float4*)&Wt[k][m0];
      float4 a1 = *(const float4*)&Wt[k][m0 + 4];
      float4 b0 = *(const float4*)&Xt[k][tx * 4];
      float4 b1 = *(const float4*)&Xt[k][64 + tx * 4];
      float av[8] = {a0.x,a0.y,a0.z,a0.w,a1.x,a1.y,a1.z,a1.w};
      float bv8[8] = {b0.x,b0.y,b0.z,b0.w,b1.x,b1.y,b1.z,b1.w};
      #pragma unroll
      for (int i = 0; i < 8; i++)
        #pragma unroll
        for (int j = 0; j < 8; j++)
          acc[i][j] = fmaf(av[i], bv8[j], acc[i][j]);
    }
    __syncthreads();
  }

  const int ch0 = mtile * 128 + m0;        // channel within 256-half buffer
  float bi[8];
  #pragma unroll
  for (int i = 0; i < 8; i++) bi[i] = bv[chalf * 256 + ch0 + i];
  #pragma unroll
  for (int jj = 0; jj < 8; jj++) {
    int n = (jj < 4) ? (tx * 4 + jj) : (64 + tx * 4 + (jj - 4));
    size_t hw = (size_t)nbase + n;
    u16* p = vdst + ((size_t)b * NHW + hw) * 256 + ch0;
    union { u16 s[8]; uint4 v; } tmp;
    #pragma unroll
    for (int i = 0; i < 8; i++) tmp.s[i] = f2h(acc[i][jj] + bi[i]);
    *(uint4*)p = tmp.v;
  }
}

// ---------------- K2: column (H-axis) energies, per (d,b,w); diag masked
__global__ __launch_bounds__(256) void energyH_kernel(u16* __restrict__ ws)
{
  const int tid = threadIdx.x;
  const int w = blockIdx.x, b = blockIdx.y, d = blockIdx.z;
  const u16* Q  = ws + ATT_E + (d == 0 ? QK1 : 0);           // d0: qy, d1: qx
  const u16* Kk = ws + ATT_E + 2*QK1 + (d == 0 ? 0 : QK1);   // d0: kx, d1: ky
  u16* att = ws;

  __shared__ float Qs[96][68];
  __shared__ float Ks[96][68];

  #pragma unroll
  for (int it = 0; it < 3; it++) {
    int li = it * 256 + tid;          // 0..767
    int row = li >> 3, c8 = li & 7;
    size_t ga = ((size_t)b * NHW + (size_t)row * 96 + w) * 64 + c8 * 8;
    uint4 pq = *(const uint4*)(Q + ga);
    uint4 pk = *(const uint4*)(Kk + ga);
    float4 fa, fb;
    unpack8v(pq, fa, fb);
    *(float4*)&Qs[row][c8*8]     = fa;
    *(float4*)&Qs[row][c8*8 + 4] = fb;
    unpack8v(pk, fa, fb);
    *(float4*)&Ks[row][c8*8]     = fa;
    *(float4*)&Ks[row][c8*8 + 4] = fb;
  }
  __syncthreads();

  const int ty = tid >> 4, tx = tid & 15;
  const int h0 = ty * 6, g0 = tx * 6;
  float acc[6][6];
  #pragma unroll
  for (int i = 0; i < 6; i++)
    #pragma unroll
    for (int j = 0; j < 6; j++) acc[i][j] = 0.f;

  for (int c4 = 0; c4 < 16; c4++) {
    float4 qv[6], kv[6];
    #pragma unroll
    for (int i = 0; i < 6; i++) qv[i] = *(const float4*)&Qs[h0 + i][c4 * 4];
    #pragma unroll
    for (int j = 0; j < 6; j++) kv[j] = *(const float4*)&Ks[g0 + j][c4 * 4];
    #pragma unroll
    for (int i = 0; i < 6; i++)
      #pragma unroll
      for (int j = 0; j < 6; j++) {
        acc[i][j] = fmaf(qv[i].x, kv[j].x, acc[i][j]);
        acc[i][j] = fmaf(qv[i].y, kv[j].y, acc[i][j]);
        acc[i][j] = fmaf(qv[i].z, kv[j].z, acc[i][j]);
        acc[i][j] = fmaf(qv[i].w, kv[j].w, acc[i][j]);
      }
  }
  #pragma unroll
  for (int i = 0; i < 6; i++) {
    int h = h0 + i;
    size_t base = ((size_t)(d * NB + b) * NHW + (size_t)h * 96 + w) * 192;
    #pragma unroll
    for (int j = 0; j < 6; j++) {
      int g = g0 + j;
      att[base + g] = f2h((g == h) ? -30000.0f : acc[i][j]);
    }
  }
}

// ---------------- K3: row (W-axis) energies, per (d,b,h)
__global__ __launch_bounds__(256) void energyW_kernel(u16* __restrict__ ws)
{
  const int tid = threadIdx.x;
  const int h = blockIdx.x, b = blockIdx.y, d = blockIdx.z;
  const u16* Q  = ws + ATT_E + (d == 0 ? QK1 : 0);
  const u16* Kk = ws + ATT_E + 2*QK1 + (d == 0 ? 0 : QK1);
  u16* att = ws;

  __shared__ float Qs[96][68];
  __shared__ float Ks[96][68];

  size_t slab = ((size_t)b * NHW + (size_t)h * 96) * 64;
  #pragma unroll
  for (int it = 0; it < 3; it++) {
    int li = it * 256 + tid;
    int row = li >> 3, c8 = li & 7;
    uint4 pq = *(const uint4*)(Q + slab + (size_t)li * 8);
    uint4 pk = *(const uint4*)(Kk + slab + (size_t)li * 8);
    float4 fa, fb;
    unpack8v(pq, fa, fb);
    *(float4*)&Qs[row][c8*8]     = fa;
    *(float4*)&Qs[row][c8*8 + 4] = fb;
    unpack8v(pk, fa, fb);
    *(float4*)&Ks[row][c8*8]     = fa;
    *(float4*)&Ks[row][c8*8 + 4] = fb;
  }
  __syncthreads();

  const int ty = tid >> 4, tx = tid & 15;
  const int w0 = ty * 6, v0 = tx * 6;
  float acc[6][6];
  #pragma unroll
  for (int i = 0; i < 6; i++)
    #pragma unroll
    for (int j = 0; j < 6; j++) acc[i][j] = 0.f;

  for (int c4 = 0; c4 < 16; c4++) {
    float4 qv[6], kv[6];
    #pragma unroll
    for (int i = 0; i < 6; i++) qv[i] = *(const float4*)&Qs[w0 + i][c4 * 4];
    #pragma unroll
    for (int j = 0; j < 6; j++) kv[j] = *(const float4*)&Ks[v0 + j][c4 * 4];
    #pragma unroll
    for (int i = 0; i < 6; i++)
      #pragma unroll
      for (int j = 0; j < 6; j++) {
        acc[i][j] = fmaf(qv[i].x, kv[j].x, acc[i][j]);
        acc[i][j] = fmaf(qv[i].y, kv[j].y, acc[i][j]);
        acc[i][j] = fmaf(qv[i].z, kv[j].z, acc[i][j]);
        acc[i][j] = fmaf(qv[i].w, kv[j].w, acc[i][j]);
      }
  }
  #pragma unroll
  for (int i = 0; i < 6; i++) {
    int wq = w0 + i;
    size_t base = ((size_t)(d * NB + b) * NHW + (size_t)h * 96 + wq) * 192;
    #pragma unroll
    for (int j = 0; j < 6; j++)
      att[base + 96 + (v0 + j)] = f2h(acc[i][j]);
  }
}

// ---------------- K4: softmax over 192 per position, in place (one wave per position)
__global__ __launch_bounds__(256) void softmax_kernel(u16* __restrict__ ws)
{
  u16* att = ws;
  const int lane = threadIdx.x & 63;
  const size_t pos = (size_t)blockIdx.x * 4 + (threadIdx.x >> 6);
  u16* p = att + pos * 192;
  float v0 = h2f(p[lane]);
  float v1 = h2f(p[lane + 64]);
  float v2 = h2f(p[lane + 128]);
  float m = fmaxf(v0, fmaxf(v1, v2));
  #pragma unroll
  for (int s = 32; s > 0; s >>= 1) m = fmaxf(m, __shfl_xor(m, s, 64));
  float e0 = __expf(v0 - m), e1 = __expf(v1 - m), e2 = __expf(v2 - m);
  float sum = e0 + e1 + e2;
  #pragma unroll
  for (int s = 32; s > 0; s >>= 1) sum += __shfl_xor(sum, s, 64);
  float inv = 1.0f / sum;
  p[lane]       = f2h(e0 * inv);
  p[lane + 64]  = f2h(e1 * inv);
  p[lane + 128] = f2h(e2 * inv);
}

// ---------------- K5: H-aggregation for (d, chalf): writes RAW outH sums to d_out
__global__ __launch_bounds__(256) void aggH_kernel(const u16* __restrict__ ws,
    float* __restrict__ out, int d, int chalf)
{
  const int tid = threadIdx.x;
  const int wi = blockIdx.x;
  const int w = (wi & 7) * 12 + (wi >> 3);   // XCD-friendly remap
  const int b = blockIdx.y;
  const u16* V = ws + ATT_E;                 // [B][HW][256] half-channel buffer
  const u16* att = ws;

  __shared__ float At[96][100];   // At[g][h]
  __shared__ u16 Vc[96][128];     // Vc[g][128-channel chunk]

  for (int it = 0; it < 5; it++) {
    int li = it * 256 + tid;
    if (li < 1152) {
      int hh = li / 12, c8 = li % 12;
      uint4 pa = *(const uint4*)(att + ((size_t)(d * NB + b) * NHW + (size_t)hh * 96 + w) * 192 + c8 * 8);
      float4 fa, fb; unpack8v(pa, fa, fb);
      int g = c8 * 8;
      At[g+0][hh] = fa.x; At[g+1][hh] = fa.y; At[g+2][hh] = fa.z; At[g+3][hh] = fa.w;
      At[g+4][hh] = fb.x; At[g+5][hh] = fb.y; At[g+6][hh] = fb.z; At[g+7][hh] = fb.w;
    }
  }
  __syncthreads();

  const int cl = (tid & 31) * 4;
  const int h0 = (tid >> 5) * 12;
  const size_t obase = (size_t)d * BCHW_ + (size_t)b * CHW_;

  for (int cc = 0; cc < 2; cc++) {
    #pragma unroll
    for (int it = 0; it < 6; it++) {
      int li = it * 256 + tid;               // 0..1535: FULL 96x128 tile
      int gg = li >> 4, c16 = li & 15;
      uint4 pv = *(const uint4*)(V + ((size_t)b * NHW + (size_t)gg * 96 + w) * 256 + cc * 128 + c16 * 8);
      *(uint4*)&Vc[gg][c16 * 8] = pv;
    }
    __syncthreads();
    float acc[12][4];
    #pragma unroll
    for (int i = 0; i < 12; i++)
      #pragma unroll
      for (int j = 0; j < 4; j++) acc[i][j] = 0.f;

    for (int g = 0; g < 96; g++) {
      uint2 rv = *(const uint2*)&Vc[g][cl];
      float va0 = h2f(rv.x & 0xffffu), va1 = h2f(rv.x >> 16);
      float va2 = h2f(rv.y & 0xffffu), va3 = h2f(rv.y >> 16);
      float4 awa = *(const float4*)&At[g][h0];
      float4 awb = *(const float4*)&At[g][h0 + 4];
      float4 awc = *(const float4*)&At[g][h0 + 8];
      float aw[12] = {awa.x,awa.y,awa.z,awa.w, awb.x,awb.y,awb.z,awb.w, awc.x,awc.y,awc.z,awc.w};
      #pragma unroll
      for (int i = 0; i < 12; i++) {
        acc[i][0] = fmaf(aw[i], va0, acc[i][0]);
        acc[i][1] = fmaf(aw[i], va1, acc[i][1]);
        acc[i][2] = fmaf(aw[i], va2, acc[i][2]);
        acc[i][3] = fmaf(aw[i], va3, acc[i][3]);
      }
    }
    #pragma unroll
    for (int j = 0; j < 4; j++) {
      int c = chalf * 256 + cc * 128 + cl + j;
      float* po = out + obase + (size_t)c * NHW + w;
      #pragma unroll
      for (int i = 0; i < 12; i++)
        po[(size_t)(h0 + i) * 96] = acc[i][j];
    }
    __syncthreads();
  }
}

// ---------------- K6: W-aggregation + gamma + residual for (d, chalf): finalizes d_out
__global__ __launch_bounds__(256) void aggW_kernel(const u16* __restrict__ ws,
    const float* __restrict__ x, const float* __restrict__ y,
    const float* __restrict__ gamma, float* __restrict__ out, int d, int chalf)
{
  const int tid = threadIdx.x;
  const int h = blockIdx.x, b = blockIdx.y;
  const u16* V = ws + ATT_E;
  const u16* att = ws;
  const float* res = d ? y : x;
  const float gm = gamma[0];

  __shared__ float At[96][100];   // At[v2][w]
  __shared__ u16 Vc[96][128];

  for (int it = 0; it < 5; it++) {
    int li = it * 256 + tid;
    if (li < 1152) {
      int ww = li / 12, c8 = li % 12;
      uint4 pa = *(const uint4*)(att + ((size_t)(d * NB + b) * NHW + (size_t)h * 96 + ww) * 192 + 96 + c8 * 8);
      float4 fa, fb; unpack8v(pa, fa, fb);
      int v = c8 * 8;
      At[v+0][ww] = fa.x; At[v+1][ww] = fa.y; At[v+2][ww] = fa.z; At[v+3][ww] = fa.w;
      At[v+4][ww] = fb.x; At[v+5][ww] = fb.y; At[v+6][ww] = fb.z; At[v+7][ww] = fb.w;
    }
  }
  __syncthreads();

  const int cl = (tid & 31) * 4;
  const int w0 = (tid >> 5) * 12;
  const u16* slab = V + ((size_t)b * NHW + (size_t)h * 96) * 256;
  const size_t obase = (size_t)d * BCHW_ + (size_t)b * CHW_ + (size_t)h * 96;
  const size_t rbase = (size_t)b * CHW_ + (size_t)h * 96;

  for (int cc = 0; cc < 2; cc++) {
    #pragma unroll
    for (int it = 0; it < 6; it++) {
      int li = it * 256 + tid;               // 0..1535: FULL 96x128 tile
      int v2 = li >> 4, c16 = li & 15;
      uint4 pv = *(const uint4*)(slab + (size_t)v2 * 256 + cc * 128 + c16 * 8);
      *(uint4*)&Vc[v2][c16 * 8] = pv;
    }
    __syncthreads();
    float acc[12][4];
    #pragma unroll
    for (int i = 0; i < 12; i++)
      #pragma unroll
      for (int j = 0; j < 4; j++) acc[i][j] = 0.f;

    for (int v2 = 0; v2 < 96; v2++) {
      uint2 rv = *(const uint2*)&Vc[v2][cl];
      float va0 = h2f(rv.x & 0xffffu), va1 = h2f(rv.x >> 16);
      float va2 = h2f(rv.y & 0xffffu), va3 = h2f(rv.y >> 16);
      float4 awa = *(const float4*)&At[v2][w0];
      float4 awb = *(const float4*)&At[v2][w0 + 4];
      float4 awc = *(const float4*)&At[v2][w0 + 8];
      float aw[12] = {awa.x,awa.y,awa.z,awa.w, awb.x,awb.y,awb.z,awb.w, awc.x,awc.y,awc.z,awc.w};
      #pragma unroll
      for (int i = 0; i < 12; i++) {
        acc[i][0] = fmaf(aw[i], va0, acc[i][0]);
        acc[i][1] = fmaf(aw[i], va1, acc[i][1]);
        acc[i][2] = fmaf(aw[i], va2, acc[i][2]);
        acc[i][3] = fmaf(aw[i], va3, acc[i][3]);
      }
    }
    #pragma unroll
    for (int j = 0; j < 4; j++) {
      int c = chalf * 256 + cc * 128 + cl + j;
      float* po = out + obase + (size_t)c * NHW + w0;
      const float* pr = res + rbase + (size_t)c * NHW + w0;
      #pragma unroll
      for (int q = 0; q < 3; q++) {
        float4 pp = *(const float4*)(po + q * 4);
        float4 rr = *(const float4*)(pr + q * 4);
        float4 oo;
        oo.x = fmaf(gm, pp.x + acc[q*4+0][j], rr.x);
        oo.y = fmaf(gm, pp.y + acc[q*4+1][j], rr.y);
        oo.z = fmaf(gm, pp.z + acc[q*4+2][j], rr.z);
        oo.w = fmaf(gm, pp.w + acc[q*4+3][j], rr.w);
        *(float4*)(po + q * 4) = oo;
      }
    }
    __syncthreads();
  }
}

extern "C" void kernel_launch(void* const* d_in, const int* in_sizes, int n_in,
                              void* d_out, int out_size, void* d_ws, size_t ws_size,
                              hipStream_t stream)
{
  const float* x  = (const float*)d_in[0];
  const float* y  = (const float*)d_in[1];
  const float* Wq = (const float*)d_in[2];
  const float* bq = (const float*)d_in[3];
  const float* Wk = (const float*)d_in[4];
  const float* bk = (const float*)d_in[5];
  const float* Wv = (const float*)d_in[6];
  const float* bv = (const float*)d_in[7];
  const float* gamma = (const float*)d_in[8];
  float* out = (float*)d_out;
  u16* ws = (u16*)d_ws;

  proj_qk_kernel<<<dim3(72, 16), 256, 0, stream>>>(x, y, Wq, bq, Wk, bk, ws);
  energyH_kernel<<<dim3(96, 8, 2), 256, 0, stream>>>(ws);
  energyW_kernel<<<dim3(96, 8, 2), 256, 0, stream>>>(ws);
  softmax_kernel<<<dim3(36864), 256, 0, stream>>>(ws);
  for (int t = 0; t < 2; t++) {
    for (int ch = 0; ch < 2; ch++) {
      proj_v_kernel<<<dim3(72, 2, 8), 256, 0, stream>>>(x, y, Wv, bv, ws, t, ch);
      aggH_kernel<<<dim3(96, 8), 256, 0, stream>>>(ws, out, t, ch);
      aggW_kernel<<<dim3(96, 8), 256, 0, stream>>>(ws, x, y, gamma, out, t, ch);
    }
  }
}